// Round 7
// baseline (724.053 us; speedup 1.0000x reference)
//
#include <hip/hip_runtime.h>

typedef unsigned short u16;
typedef __bf16 bf16t;
typedef bf16t v8bf __attribute__((ext_vector_type(8)));
typedef float v4f __attribute__((ext_vector_type(4)));

#define Bb 64
#define Tt 20
#define Tm 19
#define Pp 36
#define Vv 32000
#define Ee 300
#define Ep 320
#define Hh 512
#define Dd 512
#define Gg 2048

__device__ __forceinline__ u16 f2b(float f) {
    unsigned u = __builtin_bit_cast(unsigned, f);
    unsigned r = u + 0x7fffu + ((u >> 16) & 1u);
    return (u16)(r >> 16);
}
__device__ __forceinline__ float b2f(u16 x) {
    return __builtin_bit_cast(float, (unsigned)x << 16);
}
__device__ __forceinline__ v8bf ld8(const u16* p) {
    return *reinterpret_cast<const v8bf*>(p);
}

// ---- device-coherent (LLC) accessors: relaxed agent atomics -> plain
// global_load/store with sc0/sc1 bits (write-through to LLC, no fences).
__device__ __forceinline__ float ld_f32_coh(const float* p) {
    return __hip_atomic_load(p, __ATOMIC_RELAXED, __HIP_MEMORY_SCOPE_AGENT);
}
__device__ __forceinline__ void st_f32_coh(float* p, float v) {
    __hip_atomic_store(p, v, __ATOMIC_RELAXED, __HIP_MEMORY_SCOPE_AGENT);
}
__device__ __forceinline__ void st_u32_coh(unsigned* p, unsigned v) {
    __hip_atomic_store(p, v, __ATOMIC_RELAXED, __HIP_MEMORY_SCOPE_AGENT);
}

// Diagnostic sentinel: writes `val` into out[0..8191] (f32 pred region).
__global__ void k_sentinel_r4(float* __restrict__ out, float val)
{
    int i = blockIdx.x * 256 + threadIdx.x;
    if (i < 8192) out[i] = val;
}

// ---------------- MFMA GEMM: C[M,N] = A[M,K] * Bt[N,K]^T ----------------
// EPI 0: Cf = acc + addN[n]?          (f32 out)
// EPI 1: Cb = bf16(acc)
// EPI 4: Cb = bf16(acc + addN[n])
// EPI 5: Cb = bf16(acc + addM[m])
template<int EPI>
__global__ __launch_bounds__(256) void gemm_bt_r4(
    const u16* __restrict__ A, const u16* __restrict__ B,
    int lda, int ldb, int K,
    float* __restrict__ Cf, u16* __restrict__ Cb, int ldc,
    const float* __restrict__ addN, const float* __restrict__ addM,
    const u16* __restrict__ addMatB,
    const u16* __restrict__ wspB, const int* __restrict__ dec,
    float* __restrict__ outP)
{
    int bn = blockIdx.x, bm = blockIdx.y;
    const int tid = threadIdx.x;
    const int w = tid >> 6, l = tid & 63;
    const int lr = l & 15, lk = (l >> 4) << 3;
    const int m0 = bm * 64;
    const int n0 = bn * 64 + w * 16;
    const u16* Ap = A + (size_t)(m0 + lr) * lda + lk;
    const u16* Bp = B + (size_t)(n0 + lr) * ldb + lk;
    v4f acc0 = {0.f,0.f,0.f,0.f}, acc1 = {0.f,0.f,0.f,0.f},
        acc2 = {0.f,0.f,0.f,0.f}, acc3 = {0.f,0.f,0.f,0.f};
    for (int k = 0; k < K; k += 32) {
        v8bf bf = ld8(Bp + k);
        v8bf a0 = ld8(Ap + k);
        v8bf a1 = ld8(Ap + (size_t)16 * lda + k);
        v8bf a2 = ld8(Ap + (size_t)32 * lda + k);
        v8bf a3 = ld8(Ap + (size_t)48 * lda + k);
        acc0 = __builtin_amdgcn_mfma_f32_16x16x32_bf16(a0, bf, acc0, 0, 0, 0);
        acc1 = __builtin_amdgcn_mfma_f32_16x16x32_bf16(a1, bf, acc1, 0, 0, 0);
        acc2 = __builtin_amdgcn_mfma_f32_16x16x32_bf16(a2, bf, acc2, 0, 0, 0);
        acc3 = __builtin_amdgcn_mfma_f32_16x16x32_bf16(a3, bf, acc3, 0, 0, 0);
    }
    v4f accs[4] = {acc0, acc1, acc2, acc3};
    const int crow0 = (l >> 4) * 4;
    const int n = n0 + lr;
    #pragma unroll
    for (int i = 0; i < 4; ++i) {
        #pragma unroll
        for (int r = 0; r < 4; ++r) {
            int m = m0 + i * 16 + crow0 + r;
            float v = accs[i][r];
            if (EPI == 0) {
                if (addN) v += addN[n];
                Cf[(size_t)m * ldc + n] = v;
            } else if (EPI == 1) {
                Cb[(size_t)m * ldc + n] = f2b(v);
            } else if (EPI == 4) {
                Cb[(size_t)m * ldc + n] = f2b(v + addN[n]);
            } else if (EPI == 5) {
                Cb[(size_t)m * ldc + n] = f2b(v + addM[m]);
            }
        }
    }
}

// ---------------- dedicated prediction GEMM (pipelined, conflict-free LDS) ----------------
// outP[b*Tm+t, n] = mask * (acc + (addN[n] + addM[m] + wspB[b,n]))
// Tile 64M (one t) x 256N; K=320 in 5 chunks of 64.
// B staged in fragment-order LDS BT[ks][w][j][lane][8] -> lane-consecutive 16B
// ds_read/ds_write (conflict floor). A fragments loaded straight to registers
// (40 KB A-tile is L2-hot across the 125 bn-blocks sharing it).
// T14 pipeline: chunk k+1 global loads issued before chunk k compute.
// FP accumulation order identical to previous version (bit-identical output).
__global__ __launch_bounds__(256) void k_pred_r11(
    const u16* __restrict__ A,      // Hw  [1216][320]
    const u16* __restrict__ B,      // embp [32000][320]
    const float* __restrict__ addN, // w_lin [32000]
    const float* __restrict__ addM, // rsum  [1216] (t*64+b)
    const u16* __restrict__ wspB,   // wr_sumP [64][32000]
    const int* __restrict__ dec,
    float* __restrict__ outP)       // [64][19][32000] f32
{
    const int wg = blockIdx.x;
    const int xcd = wg & 7;
    const int g = wg >> 3;                 // 0..303
    const int bn_local = g / 19;
    const int bm = g - bn_local * 19;      // t
    const int nt = (xcd < 5) ? 16 : 15;    // 125 n-tiles over 8 XCDs
    if (bn_local >= nt) return;
    const int bn = ((xcd < 5) ? xcd * 16 : 80 + (xcd - 5) * 15) + bn_local;
    const int t = bm;
    const int n0 = bn * 256;

    __shared__ u16 BT[2][4][4][64][8];     // [ks][w][j][lane][8] = 32 KB
    u16* BTf = (u16*)BT;

    const int tid = threadIdx.x;
    const int w = tid >> 6, l = tid & 63;
    const int lr = l & 15, lk = (l >> 4) << 3;
    const int crow0 = (l >> 4) * 4;

    v4f acc[4][4];
    #pragma unroll
    for (int i = 0; i < 4; ++i)
        #pragma unroll
        for (int j = 0; j < 4; ++j) acc[i][j] = (v4f){0.f,0.f,0.f,0.f};

    // B staging slot decode (8 slots/thread): slot = tid + s*256
    //   ks = slot>>10, wq = (slot>>8)&3, j = (slot>>6)&3, ln = slot&63
    //   src = B[(n0 + wq*64 + j*16 + (ln&15))*Ep + k0 + ks*32 + ((ln>>4)<<3)]
    int brow[8], bcol[8];
    #pragma unroll
    for (int s = 0; s < 8; ++s) {
        int slot = tid + s * 256;
        int ks = slot >> 10, wq = (slot >> 8) & 3, j = (slot >> 6) & 3, ln = slot & 63;
        brow[s] = n0 + wq * 64 + j * 16 + (ln & 15);
        bcol[s] = ks * 32 + ((ln >> 4) << 3);
    }

    // ---- prologue: chunk 0 ----
    v8bf bstg[8];
    #pragma unroll
    for (int s = 0; s < 8; ++s)
        bstg[s] = ld8(B + (size_t)brow[s] * Ep + 0 + bcol[s]);
    v8bf areg[2][4];
    #pragma unroll
    for (int ks = 0; ks < 2; ++ks)
        #pragma unroll
        for (int i = 0; i < 4; ++i)
            areg[ks][i] = ld8(A + (size_t)(t * 64 + i * 16 + lr) * Ep + 0 + ks * 32 + lk);
    #pragma unroll
    for (int s = 0; s < 8; ++s)
        *reinterpret_cast<v8bf*>(&BTf[(size_t)(tid + s * 256) * 8]) = bstg[s];
    __syncthreads();

    #pragma unroll
    for (int kc = 0; kc < 5; ++kc) {
        // prefetch chunk kc+1 (global -> regs) before computing kc
        v8bf bnxt[8];
        v8bf anxt[2][4];
        if (kc < 4) {
            const int k0n = (kc + 1) * 64;
            #pragma unroll
            for (int s = 0; s < 8; ++s)
                bnxt[s] = ld8(B + (size_t)brow[s] * Ep + k0n + bcol[s]);
            #pragma unroll
            for (int ks = 0; ks < 2; ++ks)
                #pragma unroll
                for (int i = 0; i < 4; ++i)
                    anxt[ks][i] = ld8(A + (size_t)(t * 64 + i * 16 + lr) * Ep
                                        + k0n + ks * 32 + lk);
        }
        // compute chunk kc: A from regs, B from fragment-order LDS
        #pragma unroll
        for (int ks = 0; ks < 2; ++ks) {
            #pragma unroll
            for (int j = 0; j < 4; ++j) {
                v8bf bf = *reinterpret_cast<const v8bf*>(&BT[ks][w][j][l][0]);
                acc[0][j] = __builtin_amdgcn_mfma_f32_16x16x32_bf16(areg[ks][0], bf, acc[0][j], 0, 0, 0);
                acc[1][j] = __builtin_amdgcn_mfma_f32_16x16x32_bf16(areg[ks][1], bf, acc[1][j], 0, 0, 0);
                acc[2][j] = __builtin_amdgcn_mfma_f32_16x16x32_bf16(areg[ks][2], bf, acc[2][j], 0, 0, 0);
                acc[3][j] = __builtin_amdgcn_mfma_f32_16x16x32_bf16(areg[ks][3], bf, acc[3][j], 0, 0, 0);
            }
        }
        if (kc < 4) {
            __syncthreads();               // all reads of chunk kc done
            #pragma unroll
            for (int s = 0; s < 8; ++s)
                *reinterpret_cast<v8bf*>(&BTf[(size_t)(tid + s * 256) * 8]) = bnxt[s];
            #pragma unroll
            for (int ks = 0; ks < 2; ++ks)
                #pragma unroll
                for (int i = 0; i < 4; ++i)
                    areg[ks][i] = anxt[ks][i];
            __syncthreads();               // chunk kc+1 visible
        }
    }

    // epilogue — FP order identical to old EPI3: v = acc + ((addN + addM) + wsp)
    float aN[4];
    #pragma unroll
    for (int j = 0; j < 4; ++j) aN[j] = addN[n0 + w * 64 + j * 16 + lr];
    #pragma unroll
    for (int i = 0; i < 4; ++i) {
        #pragma unroll
        for (int r = 0; r < 4; ++r) {
            int b = i * 16 + crow0 + r;
            float aM = addM[t * 64 + b];
            bool live = t < dec[b];
            #pragma unroll
            for (int j = 0; j < 4; ++j) {
                int n = n0 + w * 64 + j * 16 + lr;
                float x = aN[j] + aM + b2f(wspB[(size_t)b * Vv + n]);
                float v = acc[i][j][r] + x;
                outP[((size_t)b * Tm + t) * Vv + n] = live ? v : 0.0f;
            }
        }
    }
}

// ---------------- contention-free flag-array grid barrier ----------------
__device__ __forceinline__ void gbar_r7(int* flags, int epoch) {
    __syncthreads();
    if (threadIdx.x == 0)
        __hip_atomic_store(&flags[blockIdx.x * 16], epoch,
                           __ATOMIC_RELAXED, __HIP_MEMORY_SCOPE_AGENT);
    if (threadIdx.x < 64) {
        while (__hip_atomic_load(&flags[threadIdx.x * 16],
                                 __ATOMIC_RELAXED, __HIP_MEMORY_SCOPE_AGENT) < epoch)
            __builtin_amdgcn_s_sleep(1);
    }
    __syncthreads();
}

// ---------------- fused 19-step recurrence (persistent, 64 blocks) ----------------
// r11: Wc slice stored in fragment order wldsT[k][half][lane][8] -> lane-
// consecutive 16B ds_reads (conflict floor; was 1.2M bank-conflict cycles with
// the row-major padded layout). Values & MFMA order identical to r9.
__global__ __launch_bounds__(256) void k_loop_r11(
    const u16* __restrict__ Wc, const u16* __restrict__ gates_e,
    float* __restrict__ gates,
    const float* __restrict__ sum_WH, const float* __restrict__ sum_wl,
    const float* __restrict__ wr_sumV, const float* __restrict__ r_lin,
    const float* __restrict__ RH, const u16* __restrict__ props_bf,
    const int* __restrict__ dec_i, const float* __restrict__ wh_b,
    const float* __restrict__ h_state, const float* __restrict__ c_state,
    const float* __restrict__ fb_state, u16* __restrict__ xin2s,
    u16* __restrict__ Hseq, float* __restrict__ rsum,
    float* __restrict__ out_att, int* __restrict__ flags)
{
    const int blk = blockIdx.x;            // 0..63: N-slice in G, batch in S
    const int tid = threadIdx.x;
    const int w = tid >> 6, l = tid & 63;
    const int lr = l & 15, lk = (l >> 4) << 3;
    const int m0 = w * 16;                 // G: batch-row block of this wave
    const int j0 = blk * 32;               // G: gate-column slice of this block
    const int crow0 = (l >> 4) * 4;

    __shared__ u16 wldsT[32][2][64][8];    // Wc slice, fragment order: 64 KB
    __shared__ u16 plds[Pp * Dd];          // props_bf[blk]: 36 x 512
    __shared__ float hbuf[Hh];
    __shared__ float rbuf[Pp];
    __shared__ float attbuf[Pp];
    __shared__ float red1[256], red2[256];
    __shared__ unsigned xbuf32[512];       // xin2 staging (u16[1024], 4B-aligned)
    u16* xb = (u16*)xbuf32;
    u16* wldsf = (u16*)wldsT;

    // ---- prologue: preload Wc slice (fragment order) + props row into LDS ----
    #pragma unroll
    for (int s = 0; s < 16; ++s) {
        int slot = tid + s * 256;          // 4096 slots: k(32) x h(2) x lane(64)
        int k = slot >> 7, h = (slot >> 6) & 1, ln = slot & 63;
        *reinterpret_cast<v8bf*>(&wldsf[(size_t)slot * 8]) =
            ld8(Wc + (size_t)(j0 + h * 16 + (ln & 15)) * 1024
                   + k * 32 + ((ln >> 4) << 3));
    }
    for (int idx = tid; idx < (Pp * Dd) / 8; idx += 256) {
        int off = idx << 3;
        *reinterpret_cast<v8bf*>(&plds[off]) =
            ld8(props_bf + (size_t)blk * (Pp * Dd) + off);
    }

    // ---- hoisted per-thread invariants (constant across t) ----
    const int b = blk;
    const int dec_b = dec_i[b];
    const float swh0 = sum_WH[tid], swh1 = sum_WH[tid + 256];
    const float wb0 = wh_b[tid], wb1 = wh_b[tid + 256];
    const float sumwl = sum_wl[0];
    const float wrsV = (tid < Pp) ? wr_sumV[b * Pp + tid] : 0.f;
    float rlin[9];
    #pragma unroll
    for (int i = 0; i < 9; ++i) rlin[i] = r_lin[b * Pp + (w + i * 4)];
    // persistent LSTM/feedback state in registers (global bufs are init-only)
    float cr0 = c_state[b * Hh + tid],       cr1 = c_state[b * Hh + tid + 256];
    float hr0 = h_state[b * Hh + tid],       hr1 = h_state[b * Hh + tid + 256];
    float fbr0 = fb_state[b * Hh + tid],     fbr1 = fb_state[b * Hh + tid + 256];
    __syncthreads();

    for (int t = 0; t < Tm; ++t) {
        // ---------- Phase G ----------
        {
            const u16* Ap = xin2s + (size_t)t * (Bb * 1024)
                                  + (size_t)(m0 + lr) * 1024 + lk;
            // burst-issue ALL 32 A loads (128 VGPR in flight, one LLC exposure)
            v8bf areg[32];
            #pragma unroll
            for (int k = 0; k < 32; ++k) areg[k] = ld8(Ap + k * 32);
            // gates_e prefetch (consumed after MFMAs)
            const u16* ge = gates_e + (size_t)t * (Bb * Gg);
            u16 ge0[4], ge1[4];
            size_t obase[4];
            #pragma unroll
            for (int r = 0; r < 4; ++r) {
                int bb = m0 + crow0 + r;
                size_t o0 = (size_t)bb * Gg + j0 + lr;
                obase[r] = o0;
                ge0[r] = ge[o0];
                ge1[r] = ge[o0 + 16];
            }
            v4f acc0 = {0.f,0.f,0.f,0.f}, acc1 = {0.f,0.f,0.f,0.f};
            #pragma unroll
            for (int k = 0; k < 32; ++k) {
                v8bf b0 = *reinterpret_cast<const v8bf*>(&wldsT[k][0][l][0]);
                v8bf b1 = *reinterpret_cast<const v8bf*>(&wldsT[k][1][l][0]);
                acc0 = __builtin_amdgcn_mfma_f32_16x16x32_bf16(areg[k], b0, acc0, 0, 0, 0);
                acc1 = __builtin_amdgcn_mfma_f32_16x16x32_bf16(areg[k], b1, acc1, 0, 0, 0);
            }
            #pragma unroll
            for (int r = 0; r < 4; ++r) {
                st_f32_coh(&gates[obase[r]],      acc0[r] + b2f(ge0[r]));
                st_f32_coh(&gates[obase[r] + 16], acc1[r] + b2f(ge1[r]));
            }
        }
        gbar_r7(flags, 2 * t + 1);
        // ---------- Phase S ----------
        {
            bool live = t < dec_b;
            float hn_arr[2];
            const float* g = gates + (size_t)b * Gg;
            // batch the 8 coherent gate loads up-front: one latency exposure
            float gv[8];
            #pragma unroll
            for (int q = 0; q < 2; ++q) {
                int d = tid + q * 256;
                gv[q*4+0] = ld_f32_coh(g + d);
                gv[q*4+1] = ld_f32_coh(g + 512 + d);
                gv[q*4+2] = ld_f32_coh(g + 1024 + d);
                gv[q*4+3] = ld_f32_coh(g + 1536 + d);
            }
            #pragma unroll
            for (int q = 0; q < 2; ++q) {
                int d = tid + q * 256;
                float gi = gv[q*4+0], gf = gv[q*4+1],
                      gg2 = gv[q*4+2], go = gv[q*4+3];
                float c_old = (q == 0) ? cr0 : cr1;
                float si = 1.f / (1.f + expf(-gi));
                float sf = 1.f / (1.f + expf(-gf));
                float so = 1.f / (1.f + expf(-go));
                float cn = sf * c_old + si * tanhf(gg2);
                float hn = so * tanhf(cn);
                hbuf[d] = hn;
                hn_arr[q] = hn;
                Hseq[((size_t)t * Bb + b) * Hh + d] = f2b(hn);
                if (live) {
                    if (q == 0) { cr0 = cn; hr0 = hn; }
                    else        { cr1 = cn; hr1 = hn; }
                }
                xb[Hh + d] = f2b((q == 0) ? hr0 : hr1);
            }
            red1[tid] = hn_arr[0] * swh0 + hn_arr[1] * swh1;
            red2[tid] = hn_arr[0] * wb0 + hn_arr[1] * wb1;
            __syncthreads();
            // deep-ILP RH dot: hbuf once into 8 regs, all 72 RH loads in one burst
            {
                float hv[8];
                #pragma unroll
                for (int j = 0; j < 8; ++j) hv[j] = hbuf[l + j * 64];
                float rhv[9][8];
                #pragma unroll
                for (int i = 0; i < 9; ++i) {
                    const float* rh = RH + ((size_t)b * Pp + (w + i * 4)) * Dd + l;
                    #pragma unroll
                    for (int j = 0; j < 8; ++j) rhv[i][j] = rh[j * 64];
                }
                #pragma unroll
                for (int i = 0; i < 9; ++i) {
                    float a = 0.f;
                    #pragma unroll
                    for (int j = 0; j < 8; ++j) a += rhv[i][j] * hv[j];
                    #pragma unroll
                    for (int off = 32; off > 0; off >>= 1) a += __shfl_down(a, off);
                    if (l == 0) rbuf[w + i * 4] = a + rlin[i];
                }
            }
            __syncthreads();
            for (int s = 128; s > 0; s >>= 1) {
                if (tid < s) { red1[tid] += red1[tid + s]; red2[tid] += red2[tid + s]; }
                __syncthreads();
            }
            if (tid < 64) {
                float hs = red1[0] + sumwl;
                float logit = -3.4e38f;
                if (tid < Pp) logit = hs + wrsV + rbuf[tid];
                float mx = logit;
                for (int off = 32; off > 0; off >>= 1) mx = fmaxf(mx, __shfl_down(mx, off));
                mx = __shfl(mx, 0);
                float ex = (tid < Pp) ? expf(logit - mx) : 0.f;
                float sm = ex;
                for (int off = 32; off > 0; off >>= 1) sm += __shfl_down(sm, off);
                sm = __shfl(sm, 0);
                float att = ex / sm;
                float rs = (tid < Pp) ? rbuf[tid] : 0.f;
                for (int off = 32; off > 0; off >>= 1) rs += __shfl_down(rs, off);
                if (tid == 0) rsum[t * Bb + b] = rs + red2[0];
                if (tid < Pp) {
                    attbuf[tid] = att;
                    out_att[((size_t)b * Tm + t) * Pp + tid] = live ? att : 0.f;
                }
            }
            __syncthreads();
            #pragma unroll
            for (int q = 0; q < 2; ++q) {
                int d = tid + q * 256;
                float fbn = 0.f;
                for (int pp = 0; pp < Pp; ++pp)
                    fbn += attbuf[pp] * b2f(plds[pp * Dd + d]);
                if (live) { if (q == 0) fbr0 = fbn; else fbr1 = fbn; }
                xb[d] = f2b((q == 0) ? fbr0 : fbr1);
            }
            __syncthreads();   // xbuf complete -> coherent u32 stores to slot t+1
            {
                unsigned* xg = (unsigned*)(xin2s + (size_t)(t + 1) * (Bb * 1024)
                                                 + (size_t)b * 1024);
                st_u32_coh(xg + tid, xbuf32[tid]);
                st_u32_coh(xg + tid + 256, xbuf32[tid + 256]);
            }
        }
        gbar_r7(flags, 2 * t + 2);
    }
}

// ---------------- small kernels (inputs are f32 / int32 per reference) ----------------

__global__ void k_sort_r4(const int* __restrict__ lengths,
                          int* __restrict__ sort_ind, int* __restrict__ dec_i,
                          float* __restrict__ out_dec, float* __restrict__ out_sort,
                          int* __restrict__ flags)
{
    __shared__ int len[64];
    int i = threadIdx.x;
    #pragma unroll
    for (int j = 0; j < 16; ++j) flags[i * 16 + j] = 0;  // reset barrier flags
    len[i] = lengths[i];
    __syncthreads();
    int li = len[i];
    int rank = 0;
    for (int j = 0; j < 64; ++j) {
        int lj = len[j];
        rank += (lj > li) || (lj == li && j < i);
    }
    sort_ind[rank] = i;
    dec_i[rank] = li - 1;
    out_sort[rank] = (float)i;
    out_dec[rank] = (float)(li - 1);
}

__global__ void k_gather_r4(const float* __restrict__ h0, const int* __restrict__ captions,
                            const int* __restrict__ sort_ind,
                            float* __restrict__ h_state, float* __restrict__ c_state,
                            float* __restrict__ fb_state, u16* __restrict__ xin2,
                            int* __restrict__ caps_s, float* __restrict__ out_caps)
{
    int b = blockIdx.x, tid = threadIdx.x;
    int src = sort_ind[b];
    for (int d = tid; d < Hh; d += 256) {
        float v = h0[(size_t)src * Hh + d];
        h_state[b * Hh + d] = v;
        c_state[b * Hh + d] = v;
        fb_state[b * Hh + d] = 0.f;
        xin2[(size_t)b * 1024 + d] = 0;
        xin2[(size_t)b * 1024 + Hh + d] = f2b(v);
    }
    if (tid < Tt) {
        int cp = captions[src * Tt + tid];
        caps_s[b * Tt + tid] = cp;
        if (tid >= 1) out_caps[b * Tm + (tid - 1)] = (float)cp;
    }
}

__global__ void k_props_r4(const float* __restrict__ props, const int* __restrict__ sort_ind,
                           const float* __restrict__ wr_b,
                           u16* __restrict__ props_bf, u16* __restrict__ S_bf,
                           float* __restrict__ swrb)
{
    int b = blockIdx.x, tid = threadIdx.x;
    int src = sort_ind[b];
    float s0 = 0.f, s1 = 0.f;
    for (int pp = 0; pp < Pp; ++pp) {
        size_t si = ((size_t)src * Pp + pp) * Dd;
        size_t di = ((size_t)b * Pp + pp) * Dd;
        float v0 = props[si + tid];
        float v1 = props[si + tid + 256];
        props_bf[di + tid] = f2b(v0);
        props_bf[di + tid + 256] = f2b(v1);
        s0 += v0; s1 += v1;
    }
    S_bf[b * Dd + tid] = f2b(s0);
    S_bf[b * Dd + tid + 256] = f2b(s1);
    float part = s0 * wr_b[tid] + s1 * wr_b[tid + 256];
    __shared__ float red[256];
    red[tid] = part;
    __syncthreads();
    for (int s = 128; s > 0; s >>= 1) {
        if (tid < s) red[tid] += red[tid + s];
        __syncthreads();
    }
    if (tid == 0) swrb[b] = red[0];
}

__global__ void k_embcast_r4(const float* __restrict__ emb_W, const float* __restrict__ w_W,
                             const float* __restrict__ w_b,
                             u16* __restrict__ embp, float* __restrict__ w_lin)
{
    int v = blockIdx.x * 4 + (threadIdx.x >> 6);
    int l = threadIdx.x & 63;
    if (v >= Vv) return;
    float acc = 0.f;
    for (int e = l; e < Ep; e += 64) {
        float x = (e < Ee) ? emb_W[(size_t)v * Ee + e] : 0.f;
        embp[(size_t)v * Ep + e] = f2b(x);
        if (e < Ee) acc += x * w_W[e];
    }
    for (int off = 32; off > 0; off >>= 1) acc += __shfl_down(acc, off);
    if (l == 0) w_lin[v] = acc + w_b[0];
}

__global__ void k_colsumA_r4(const float* __restrict__ emb_W, float* __restrict__ partial)
{
    int blk = blockIdx.x, e = threadIdx.x; // 320 threads
    float s = 0.f;
    int r0 = blk * 100;
    if (e < Ee)
        for (int r = 0; r < 100; ++r) s += emb_W[(size_t)(r0 + r) * Ee + e];
    partial[blk * Ep + e] = (e < Ee) ? s : 0.f;
}

__global__ void k_colsumB_r4(const float* __restrict__ partial, const float* __restrict__ w_W,
                             const float* __restrict__ w_b,
                             float* __restrict__ colsum, float* __restrict__ sum_wl)
{
    int e = threadIdx.x; // 320 threads
    float s = 0.f;
    for (int b = 0; b < 320; ++b) s += partial[b * Ep + e];
    colsum[e] = s;
    __shared__ float red[512];
    red[e] = (e < Ee) ? s * w_W[e] : 0.f;
    if (e < 192) red[320 + e] = 0.f;
    __syncthreads();
    for (int st = 256; st > 0; st >>= 1) {
        if (e < st) red[e] += red[e + st];
        __syncthreads();
    }
    if (e == 0) sum_wl[0] = red[0] + 32000.f * w_b[0];
}

__global__ void k_sums_r4(const float* __restrict__ colsum,
                          const float* __restrict__ wh_W, const float* __restrict__ wh_b,
                          const float* __restrict__ wr_W, const float* __restrict__ wr_b,
                          float* __restrict__ sum_WH, float* __restrict__ sum_WRp)
{
    int g = blockIdx.x * 64 + threadIdx.x;
    const float* W; const float* bias; float* out; int idx;
    if (g < Hh) { W = wh_W; bias = wh_b; out = sum_WH; idx = g; }
    else { W = wr_W; bias = wr_b; out = sum_WRp; idx = g - Hh; }
    float s = 0.f;
    for (int e = 0; e < Ee; ++e) s += colsum[e] * W[(size_t)idx * Ee + e];
    out[idx] = s + 32000.f * bias[idx];
}

__global__ void k_rlin_r4(const u16* __restrict__ props_bf, const float* __restrict__ r_W,
                          const float* __restrict__ r_b, const float* __restrict__ sum_WRp,
                          float* __restrict__ r_lin, float* __restrict__ wr_sumV)
{
    int b = blockIdx.x;
    int w = threadIdx.x >> 6, l = threadIdx.x & 63;
    for (int pp = w; pp < Pp; pp += 4) {
        const u16* row = props_bf + ((size_t)b * Pp + pp) * Dd;
        float a = 0.f, c = 0.f;
        for (int d = l; d < Dd; d += 64) {
            float x = b2f(row[d]);
            a += x * r_W[d];
            c += x * sum_WRp[d];
        }
        for (int off = 32; off > 0; off >>= 1) {
            a += __shfl_down(a, off);
            c += __shfl_down(c, off);
        }
        if (l == 0) {
            r_lin[b * Pp + pp] = a + r_b[0];
            wr_sumV[b * Pp + pp] = c;
        }
    }
}

__global__ void k_castwc_r4(const float* __restrict__ W_ih, const float* __restrict__ W_hh,
                            u16* __restrict__ Wc, u16* __restrict__ WihE)
{
    int j = blockIdx.x * 4 + (threadIdx.x >> 6);
    int l = threadIdx.x & 63;
    for (int k = l; k < 1024; k += 64) {
        float v = (k < 512) ? W_ih[(size_t)j * 812 + 300 + k]
                            : W_hh[(size_t)j * 512 + (k - 512)];
        Wc[(size_t)j * 1024 + k] = f2b(v);
    }
    for (int e = l; e < Ep; e += 64) {
        float v = (e < Ee) ? W_ih[(size_t)j * 812 + e] : 0.f;
        WihE[(size_t)j * Ep + e] = f2b(v);
    }
}

__global__ void k_castwh_r4(const float* __restrict__ wh_W, const float* __restrict__ wr_W,
                            u16* __restrict__ BtWh, u16* __restrict__ BtWr)
{
    int e = blockIdx.x;
    const float* W; u16* O;
    if (e < Ep) { W = wh_W; O = BtWh; }
    else { W = wr_W; O = BtWr; e -= Ep; }
    for (int h = threadIdx.x; h < Hh; h += 256) {
        float v = (e < Ee) ? W[(size_t)h * Ee + e] : 0.f;
        O[(size_t)e * Hh + h] = f2b(v);
    }
}

__global__ void k_castrh_r4(const float* __restrict__ rh_W, u16* __restrict__ rh_bf)
{
    int h = blockIdx.x * 4 + (threadIdx.x >> 6);
    int l = threadIdx.x & 63;
    for (int d = l; d < Dd; d += 64)
        rh_bf[(size_t)h * Dd + d] = f2b(rh_W[(size_t)h * Dd + d]);
}

__global__ void k_biascat_r4(const float* __restrict__ b_ih, const float* __restrict__ b_hh,
                             float* __restrict__ bias_cat)
{
    int j = blockIdx.x * 256 + threadIdx.x;
    bias_cat[j] = b_ih[j] + b_hh[j];
}

__global__ void k_embs_r4(const u16* __restrict__ embp, const int* __restrict__ caps_s,
                          u16* __restrict__ emb_s)
{
    int m = blockIdx.x * 4 + (threadIdx.x >> 6);
    int l = threadIdx.x & 63;
    int t = m >> 6, b = m & 63;
    int cap = caps_s[b * Tt + t];
    cap = cap < 0 ? 0 : (cap > Vv - 1 ? Vv - 1 : cap);
    const u16* src = embp + (size_t)cap * Ep;
    u16* dst = emb_s + (size_t)m * Ep;
    for (int e = l; e < Ep; e += 64) dst[e] = src[e];
}

extern "C" void kernel_launch(void* const* d_in, const int* in_sizes, int n_in,
                              void* d_out, int out_size, void* d_ws, size_t ws_size,
                              hipStream_t stream) {
    float* out = (float*)d_out;   // outputs are FLOAT32 (reference dtype)
    float* out_pred = out;
    float* out_att  = out + (size_t)Bb * Tm * Vv;
    float* out_caps = out_att + (size_t)Bb * Tm * Pp;
    float* out_dec  = out_caps + Bb * Tm;
    float* out_sort = out_dec + Bb;

    // ---- assumption guards (diagnostic sentinels) ----
    if (n_in != 19) {
        k_sentinel_r4<<<32, 256, 0, stream>>>(out_pred, 10240.f);
        return;
    }
    static const int exp_sizes[19] = {
        Bb * Hh, Bb * Pp * Dd, Bb * Tt, Bb, Vv * Ee,
        Gg * (Ee + Dd), Gg * Hh, Gg, Gg,
        Hh * Ee, Hh, Dd * Ee, Dd, Hh * Dd, Hh, Ee, 1, Dd, 1
    };
    for (int i = 0; i < 19; ++i) {
        if (in_sizes[i] != exp_sizes[i]) {
            k_sentinel_r4<<<32, 256, 0, stream>>>(out_pred, 10752.f + 256.f * i);
            return;
        }
    }
    const int exp_out = Bb * Tm * Vv + Bb * Tm * Pp + Bb * Tm + Bb + Bb;
    if (out_size != exp_out) {
        k_sentinel_r4<<<32, 256, 0, stream>>>(out_pred, 11264.f);
        return;
    }

    char* p = (char*)d_ws;
    auto alloc = [&](size_t bytes) -> char* {
        char* r = p;
        p += (bytes + 255) & ~(size_t)255;
        return r;
    };
    int*   i_sort   = (int*)alloc(Bb * 4);
    int*   i_dec    = (int*)alloc(Bb * 4);
    int*   caps_s   = (int*)alloc(Bb * Tt * 4);
    float* h_state  = (float*)alloc(Bb * Hh * 4);
    float* c_state  = (float*)alloc(Bb * Hh * 4);
    float* fb_state = (float*)alloc(Bb * Hh * 4);
    float* swrb     = (float*)alloc(Bb * 4);
    float* gates    = (float*)alloc((size_t)Bb * Gg * 4);
    float* rsum     = (float*)alloc(Tm * Bb * 4);
    float* colsum   = (float*)alloc(Ep * 4);
    float* partialc = (float*)alloc(320 * Ep * 4);
    float* w_lin    = (float*)alloc((size_t)Vv * 4);
    float* sum_WH   = (float*)alloc(Hh * 4);
    float* sum_WRp  = (float*)alloc(Dd * 4);
    float* sum_wl   = (float*)alloc(256);
    float* r_lin    = (float*)alloc(Bb * Pp * 4);
    float* wr_sumV  = (float*)alloc(Bb * Pp * 4);
    float* bias_cat = (float*)alloc(Gg * 4);
    float* RH       = (float*)alloc((size_t)Bb * Pp * Hh * 4);
    int*   flags    = (int*)alloc(Bb * 16 * 4);   // 64 cache lines, one per block
    u16*   gates_e  = (u16*)alloc((size_t)Tm * Bb * Gg * 2);
    u16*   wr_sumP  = (u16*)alloc((size_t)Bb * Vv * 2);
    u16*   embp     = (u16*)alloc((size_t)Vv * Ep * 2);
    u16*   emb_s    = (u16*)alloc((size_t)Tm * Bb * Ep * 2);
    u16*   BtWh     = (u16*)alloc((size_t)Ep * Hh * 2);
    u16*   BtWr     = (u16*)alloc((size_t)Ep * Hh * 2);
    u16*   rh_bf    = (u16*)alloc((size_t)Hh * Dd * 2);
    u16*   WihE     = (u16*)alloc((size_t)Gg * Ep * 2);
    u16*   Wc       = (u16*)alloc((size_t)Gg * 1024 * 2);
    u16*   props_bf = (u16*)alloc((size_t)Bb * Pp * Dd * 2);
    u16*   S_bf     = (u16*)alloc(Bb * Dd * 2);
    u16*   Sw       = (u16*)alloc(Bb * Ep * 2);
    u16*   xin2s    = (u16*)alloc((size_t)(Tm + 1) * Bb * 1024 * 2);  // t-versioned
    u16*   Hseq     = (u16*)alloc((size_t)Tm * Bb * Hh * 2);
    u16*   Hw       = (u16*)alloc((size_t)Tm * Bb * Ep * 2);
    size_t needed = (size_t)(p - (char*)d_ws);
    if (ws_size < needed) {
        k_sentinel_r4<<<32, 256, 0, stream>>>(out_pred, 10496.f);
        return;
    }

    const float* h0      = (const float*)d_in[0];
    const float* props   = (const float*)d_in[1];
    const int*   captions= (const int*)d_in[2];
    const int*   cap_len = (const int*)d_in[3];
    const float* emb_W   = (const float*)d_in[4];
    const float* W_ih    = (const float*)d_in[5];
    const float* W_hh    = (const float*)d_in[6];
    const float* b_ih    = (const float*)d_in[7];
    const float* b_hh    = (const float*)d_in[8];
    const float* wh_W    = (const float*)d_in[9];
    const float* wh_b    = (const float*)d_in[10];
    const float* wr_W    = (const float*)d_in[11];
    const float* wr_b    = (const float*)d_in[12];
    const float* rh_W    = (const float*)d_in[13];
    const float* rh_b    = (const float*)d_in[14];
    const float* w_W     = (const float*)d_in[15];
    const float* w_b     = (const float*)d_in[16];
    const float* r_W     = (const float*)d_in[17];
    const float* r_b     = (const float*)d_in[18];

    k_sort_r4<<<1, 64, 0, stream>>>(cap_len, i_sort, i_dec, out_dec, out_sort, flags);
    k_biascat_r4<<<Gg / 256, 256, 0, stream>>>(b_ih, b_hh, bias_cat);
    k_embcast_r4<<<Vv / 4, 256, 0, stream>>>(emb_W, w_W, w_b, embp, w_lin);
    k_colsumA_r4<<<320, 320, 0, stream>>>(emb_W, partialc);
    k_colsumB_r4<<<1, 320, 0, stream>>>(partialc, w_W, w_b, colsum, sum_wl);
    k_sums_r4<<<16, 64, 0, stream>>>(colsum, wh_W, wh_b, wr_W, wr_b, sum_WH, sum_WRp);
    k_gather_r4<<<Bb, 256, 0, stream>>>(h0, captions, i_sort, h_state, c_state,
                                        fb_state, xin2s, caps_s, out_caps);
    k_props_r4<<<Bb, 256, 0, stream>>>(props, i_sort, wr_b, props_bf, S_bf, swrb);
    k_rlin_r4<<<Bb, 256, 0, stream>>>(props_bf, r_W, r_b, sum_WRp, r_lin, wr_sumV);
    k_castwc_r4<<<Gg / 4, 256, 0, stream>>>(W_ih, W_hh, Wc, WihE);
    k_castwh_r4<<<2 * Ep, 256, 0, stream>>>(wh_W, wr_W, BtWh, BtWr);
    k_castrh_r4<<<Hh / 4, 256, 0, stream>>>(rh_W, rh_bf);
    k_embs_r4<<<(Tm * Bb) / 4, 256, 0, stream>>>(embp, caps_s, emb_s);

    // gates_e = bf16(emb_s @ WihE^T + (b_ih + b_hh))
    gemm_bt_r4<4><<<dim3(Gg / 64, (Tm * Bb) / 64), 256, 0, stream>>>(
        emb_s, WihE, Ep, Ep, Ep, nullptr, gates_e, Gg,
        bias_cat, nullptr, nullptr, nullptr, nullptr, nullptr);
    // RH = props @ rh_W^T + rh_b
    gemm_bt_r4<0><<<dim3(Hh / 64, (Bb * Pp) / 64), 256, 0, stream>>>(
        props_bf, rh_bf, Dd, Dd, Dd, RH, nullptr, Hh,
        rh_b, nullptr, nullptr, nullptr, nullptr, nullptr);
    // Sw = bf16(S @ wr_W)
    gemm_bt_r4<1><<<dim3(Ep / 64, 1), 256, 0, stream>>>(
        S_bf, BtWr, Dd, Hh, Dd, nullptr, Sw, Ep,
        nullptr, nullptr, nullptr, nullptr, nullptr, nullptr);
    // wr_sumP = bf16(Sw @ embp^T + swrb[b])
    gemm_bt_r4<5><<<dim3(Vv / 64, 1), 256, 0, stream>>>(
        Sw, embp, Ep, Ep, Ep, nullptr, wr_sumP, Vv,
        nullptr, swrb, nullptr, nullptr, nullptr, nullptr);

    // ---- fused 19-step recurrence: one persistent kernel, 64 co-resident blocks ----
    k_loop_r11<<<Bb, 256, 0, stream>>>(Wc, gates_e, gates, sum_WH, sum_wl, wr_sumV,
                                       r_lin, RH, props_bf, i_dec, wh_b,
                                       h_state, c_state, fb_state, xin2s, Hseq,
                                       rsum, out_att, flags);

    // Hw = bf16(Hseq @ wh_W)
    gemm_bt_r4<1><<<dim3(Ep / 64, (Tm * Bb) / 64), 256, 0, stream>>>(
        Hseq, BtWh, Hh, Hh, Hh, nullptr, Hw, Ep,
        nullptr, nullptr, nullptr, nullptr, nullptr, nullptr);
    // predictions (f32, masked, direct to d_out) — pipelined conflict-free kernel
    k_pred_r11<<<dim3(8 * 304), 256, 0, stream>>>(
        Hw, embp, w_lin, rsum, wr_sumP, i_dec, out_pred);
}

// Round 8
// 641.398 us; speedup vs baseline: 1.1289x; 1.1289x over previous
//
#include <hip/hip_runtime.h>

typedef unsigned short u16;
typedef __bf16 bf16t;
typedef bf16t v8bf __attribute__((ext_vector_type(8)));
typedef float v4f __attribute__((ext_vector_type(4)));

#define Bb 64
#define Tt 20
#define Tm 19
#define Pp 36
#define Vv 32000
#define Ee 300
#define Ep 320
#define Hh 512
#define Dd 512
#define Gg 2048

__device__ __forceinline__ u16 f2b(float f) {
    unsigned u = __builtin_bit_cast(unsigned, f);
    unsigned r = u + 0x7fffu + ((u >> 16) & 1u);
    return (u16)(r >> 16);
}
__device__ __forceinline__ float b2f(u16 x) {
    return __builtin_bit_cast(float, (unsigned)x << 16);
}
__device__ __forceinline__ v8bf ld8(const u16* p) {
    return *reinterpret_cast<const v8bf*>(p);
}

// ---- device-coherent (LLC) accessors ----
__device__ __forceinline__ float ld_f32_coh(const float* p) {
    return __hip_atomic_load(p, __ATOMIC_RELAXED, __HIP_MEMORY_SCOPE_AGENT);
}
__device__ __forceinline__ void st_f32_coh(float* p, float v) {
    __hip_atomic_store(p, v, __ATOMIC_RELAXED, __HIP_MEMORY_SCOPE_AGENT);
}
__device__ __forceinline__ void st_u32_coh(unsigned* p, unsigned v) {
    __hip_atomic_store(p, v, __ATOMIC_RELAXED, __HIP_MEMORY_SCOPE_AGENT);
}

// Diagnostic sentinel: writes `val` into out[0..8191] (f32 pred region).
__global__ void k_sentinel_r4(float* __restrict__ out, float val)
{
    int i = blockIdx.x * 256 + threadIdx.x;
    if (i < 8192) out[i] = val;
}

// ---------------- MFMA GEMM: C[M,N] = A[M,K] * Bt[N,K]^T ----------------
// EPI 0: Cf = acc + addN[n]?          (f32 out)
// EPI 1: Cb = bf16(acc)
// EPI 4: Cb = bf16(acc + addN[n])
// EPI 5: Cb = bf16(acc + addM[m])
template<int EPI>
__global__ __launch_bounds__(256) void gemm_bt_r4(
    const u16* __restrict__ A, const u16* __restrict__ B,
    int lda, int ldb, int K,
    float* __restrict__ Cf, u16* __restrict__ Cb, int ldc,
    const float* __restrict__ addN, const float* __restrict__ addM,
    const u16* __restrict__ addMatB,
    const u16* __restrict__ wspB, const int* __restrict__ dec,
    float* __restrict__ outP)
{
    int bn = blockIdx.x, bm = blockIdx.y;
    const int tid = threadIdx.x;
    const int w = tid >> 6, l = tid & 63;
    const int lr = l & 15, lk = (l >> 4) << 3;
    const int m0 = bm * 64;
    const int n0 = bn * 64 + w * 16;
    const u16* Ap = A + (size_t)(m0 + lr) * lda + lk;
    const u16* Bp = B + (size_t)(n0 + lr) * ldb + lk;
    v4f acc0 = {0.f,0.f,0.f,0.f}, acc1 = {0.f,0.f,0.f,0.f},
        acc2 = {0.f,0.f,0.f,0.f}, acc3 = {0.f,0.f,0.f,0.f};
    for (int k = 0; k < K; k += 32) {
        v8bf bf = ld8(Bp + k);
        v8bf a0 = ld8(Ap + k);
        v8bf a1 = ld8(Ap + (size_t)16 * lda + k);
        v8bf a2 = ld8(Ap + (size_t)32 * lda + k);
        v8bf a3 = ld8(Ap + (size_t)48 * lda + k);
        acc0 = __builtin_amdgcn_mfma_f32_16x16x32_bf16(a0, bf, acc0, 0, 0, 0);
        acc1 = __builtin_amdgcn_mfma_f32_16x16x32_bf16(a1, bf, acc1, 0, 0, 0);
        acc2 = __builtin_amdgcn_mfma_f32_16x16x32_bf16(a2, bf, acc2, 0, 0, 0);
        acc3 = __builtin_amdgcn_mfma_f32_16x16x32_bf16(a3, bf, acc3, 0, 0, 0);
    }
    v4f accs[4] = {acc0, acc1, acc2, acc3};
    const int crow0 = (l >> 4) * 4;
    const int n = n0 + lr;
    #pragma unroll
    for (int i = 0; i < 4; ++i) {
        #pragma unroll
        for (int r = 0; r < 4; ++r) {
            int m = m0 + i * 16 + crow0 + r;
            float v = accs[i][r];
            if (EPI == 0) {
                if (addN) v += addN[n];
                Cf[(size_t)m * ldc + n] = v;
            } else if (EPI == 1) {
                Cb[(size_t)m * ldc + n] = f2b(v);
            } else if (EPI == 4) {
                Cb[(size_t)m * ldc + n] = f2b(v + addN[n]);
            } else if (EPI == 5) {
                Cb[(size_t)m * ldc + n] = f2b(v + addM[m]);
            }
        }
    }
}

// ---------------- dedicated prediction GEMM (LDS-staged, 64x256 tile) ----------------
// REVERTED to the r10 version (measured-good; r11's reg-prefetch pipeline
// over-spent VGPRs and regressed ~60 us).
__global__ __launch_bounds__(256) void k_pred_r10(
    const u16* __restrict__ A,      // Hw  [1216][320]
    const u16* __restrict__ B,      // embp [32000][320]
    const float* __restrict__ addN, // w_lin [32000]
    const float* __restrict__ addM, // rsum  [1216] (t*64+b)
    const u16* __restrict__ wspB,   // wr_sumP [64][32000]
    const int* __restrict__ dec,
    float* __restrict__ outP)       // [64][19][32000] f32
{
    const int wg = blockIdx.x;
    const int xcd = wg & 7;
    const int g = wg >> 3;                 // 0..303
    const int bn_local = g / 19;
    const int bm = g - bn_local * 19;      // t
    const int nt = (xcd < 5) ? 16 : 15;    // 125 n-tiles over 8 XCDs
    if (bn_local >= nt) return;
    const int bn = ((xcd < 5) ? xcd * 16 : 80 + (xcd - 5) * 15) + bn_local;
    const int t = bm;
    const int n0 = bn * 256;

    __shared__ u16 As[64][72];             // 9.2 KB
    __shared__ u16 Bs[256][72];            // 36.9 KB

    const int tid = threadIdx.x;
    const int w = tid >> 6, l = tid & 63;
    const int lr = l & 15, lk = (l >> 4) << 3;
    const int crow0 = (l >> 4) * 4;

    v4f acc[4][4];
    #pragma unroll
    for (int i = 0; i < 4; ++i)
        #pragma unroll
        for (int j = 0; j < 4; ++j) acc[i][j] = (v4f){0.f,0.f,0.f,0.f};

    for (int kc = 0; kc < 5; ++kc) {
        const int k0 = kc * 64;
        __syncthreads();                   // protect previous chunk's reads
        #pragma unroll
        for (int s = 0; s < 2; ++s) {
            int slot = tid + s * 256;
            int row = slot >> 3, c8 = (slot & 7) << 3;
            *reinterpret_cast<v8bf*>(&As[row][c8]) =
                ld8(A + (size_t)(t * 64 + row) * Ep + k0 + c8);
        }
        #pragma unroll
        for (int s = 0; s < 8; ++s) {
            int slot = tid + s * 256;
            int row = slot >> 3, c8 = (slot & 7) << 3;
            *reinterpret_cast<v8bf*>(&Bs[row][c8]) =
                ld8(B + (size_t)(n0 + row) * Ep + k0 + c8);
        }
        __syncthreads();
        #pragma unroll
        for (int ks = 0; ks < 2; ++ks) {
            const int kk = ks * 32 + lk;
            v8bf a0 = *reinterpret_cast<const v8bf*>(&As[lr][kk]);
            v8bf a1 = *reinterpret_cast<const v8bf*>(&As[16 + lr][kk]);
            v8bf a2 = *reinterpret_cast<const v8bf*>(&As[32 + lr][kk]);
            v8bf a3 = *reinterpret_cast<const v8bf*>(&As[48 + lr][kk]);
            #pragma unroll
            for (int j = 0; j < 4; ++j) {
                v8bf bf = *reinterpret_cast<const v8bf*>(&Bs[w * 64 + j * 16 + lr][kk]);
                acc[0][j] = __builtin_amdgcn_mfma_f32_16x16x32_bf16(a0, bf, acc[0][j], 0, 0, 0);
                acc[1][j] = __builtin_amdgcn_mfma_f32_16x16x32_bf16(a1, bf, acc[1][j], 0, 0, 0);
                acc[2][j] = __builtin_amdgcn_mfma_f32_16x16x32_bf16(a2, bf, acc[2][j], 0, 0, 0);
                acc[3][j] = __builtin_amdgcn_mfma_f32_16x16x32_bf16(a3, bf, acc[3][j], 0, 0, 0);
            }
        }
    }

    // epilogue — FP order identical to old EPI3: v = acc + ((addN + addM) + wsp)
    float aN[4];
    #pragma unroll
    for (int j = 0; j < 4; ++j) aN[j] = addN[n0 + w * 64 + j * 16 + lr];
    #pragma unroll
    for (int i = 0; i < 4; ++i) {
        #pragma unroll
        for (int r = 0; r < 4; ++r) {
            int b = i * 16 + crow0 + r;
            float aM = addM[t * 64 + b];
            bool live = t < dec[b];
            #pragma unroll
            for (int j = 0; j < 4; ++j) {
                int n = n0 + w * 64 + j * 16 + lr;
                float x = aN[j] + aM + b2f(wspB[(size_t)b * Vv + n]);
                float v = acc[i][j][r] + x;
                outP[((size_t)b * Tm + t) * Vv + n] = live ? v : 0.0f;
            }
        }
    }
}

// ---------------- contention-free flag-array grid barrier ----------------
__device__ __forceinline__ void gbar_r7(int* flags, int epoch) {
    __syncthreads();
    if (threadIdx.x == 0)
        __hip_atomic_store(&flags[blockIdx.x * 16], epoch,
                           __ATOMIC_RELAXED, __HIP_MEMORY_SCOPE_AGENT);
    if (threadIdx.x < 64) {
        while (__hip_atomic_load(&flags[threadIdx.x * 16],
                                 __ATOMIC_RELAXED, __HIP_MEMORY_SCOPE_AGENT) < epoch)
            __builtin_amdgcn_s_sleep(1);
    }
    __syncthreads();
}

// ---------------- fused 19-step recurrence (persistent, 64 blocks) ----------------
// r12: r11 + RH tile hoisted into registers across all 19 steps (t-invariant;
// removes 72 L2 loads from every S-phase critical path; +72 VGPR is free at
// 1 block/CU). FMA order identical -> bit-identical output.
__global__ __launch_bounds__(256) void k_loop_r12(
    const u16* __restrict__ Wc, const u16* __restrict__ gates_e,
    float* __restrict__ gates,
    const float* __restrict__ sum_WH, const float* __restrict__ sum_wl,
    const float* __restrict__ wr_sumV, const float* __restrict__ r_lin,
    const float* __restrict__ RH, const u16* __restrict__ props_bf,
    const int* __restrict__ dec_i, const float* __restrict__ wh_b,
    const float* __restrict__ h_state, const float* __restrict__ c_state,
    const float* __restrict__ fb_state, u16* __restrict__ xin2s,
    u16* __restrict__ Hseq, float* __restrict__ rsum,
    float* __restrict__ out_att, int* __restrict__ flags)
{
    const int blk = blockIdx.x;            // 0..63: N-slice in G, batch in S
    const int tid = threadIdx.x;
    const int w = tid >> 6, l = tid & 63;
    const int lr = l & 15, lk = (l >> 4) << 3;
    const int m0 = w * 16;                 // G: batch-row block of this wave
    const int j0 = blk * 32;               // G: gate-column slice of this block
    const int crow0 = (l >> 4) * 4;

    __shared__ u16 wldsT[32][2][64][8];    // Wc slice, fragment order: 64 KB
    __shared__ u16 plds[Pp * Dd];          // props_bf[blk]: 36 x 512
    __shared__ float hbuf[Hh];
    __shared__ float rbuf[Pp];
    __shared__ float attbuf[Pp];
    __shared__ float red1[256], red2[256];
    __shared__ unsigned xbuf32[512];       // xin2 staging (u16[1024], 4B-aligned)
    u16* xb = (u16*)xbuf32;
    u16* wldsf = (u16*)wldsT;

    // ---- prologue: preload Wc slice (fragment order) + props row into LDS ----
    #pragma unroll
    for (int s = 0; s < 16; ++s) {
        int slot = tid + s * 256;          // 4096 slots: k(32) x h(2) x lane(64)
        int k = slot >> 7, h = (slot >> 6) & 1, ln = slot & 63;
        *reinterpret_cast<v8bf*>(&wldsf[(size_t)slot * 8]) =
            ld8(Wc + (size_t)(j0 + h * 16 + (ln & 15)) * 1024
                   + k * 32 + ((ln >> 4) << 3));
    }
    for (int idx = tid; idx < (Pp * Dd) / 8; idx += 256) {
        int off = idx << 3;
        *reinterpret_cast<v8bf*>(&plds[off]) =
            ld8(props_bf + (size_t)blk * (Pp * Dd) + off);
    }

    // ---- hoisted per-thread invariants (constant across t) ----
    const int b = blk;
    const int dec_b = dec_i[b];
    const float swh0 = sum_WH[tid], swh1 = sum_WH[tid + 256];
    const float wb0 = wh_b[tid], wb1 = wh_b[tid + 256];
    const float sumwl = sum_wl[0];
    const float wrsV = (tid < Pp) ? wr_sumV[b * Pp + tid] : 0.f;
    float rlin[9];
    #pragma unroll
    for (int i = 0; i < 9; ++i) rlin[i] = r_lin[b * Pp + (w + i * 4)];
    // RH tile in registers for the whole loop (t-invariant)
    float rhv[9][8];
    #pragma unroll
    for (int i = 0; i < 9; ++i) {
        const float* rh = RH + ((size_t)b * Pp + (w + i * 4)) * Dd + l;
        #pragma unroll
        for (int j = 0; j < 8; ++j) rhv[i][j] = rh[j * 64];
    }
    // persistent LSTM/feedback state in registers (global bufs are init-only)
    float cr0 = c_state[b * Hh + tid],       cr1 = c_state[b * Hh + tid + 256];
    float hr0 = h_state[b * Hh + tid],       hr1 = h_state[b * Hh + tid + 256];
    float fbr0 = fb_state[b * Hh + tid],     fbr1 = fb_state[b * Hh + tid + 256];
    __syncthreads();

    for (int t = 0; t < Tm; ++t) {
        // ---------- Phase G ----------
        {
            const u16* Ap = xin2s + (size_t)t * (Bb * 1024)
                                  + (size_t)(m0 + lr) * 1024 + lk;
            // burst-issue ALL 32 A loads (128 VGPR in flight, one LLC exposure)
            v8bf areg[32];
            #pragma unroll
            for (int k = 0; k < 32; ++k) areg[k] = ld8(Ap + k * 32);
            // gates_e prefetch (consumed after MFMAs)
            const u16* ge = gates_e + (size_t)t * (Bb * Gg);
            u16 ge0[4], ge1[4];
            size_t obase[4];
            #pragma unroll
            for (int r = 0; r < 4; ++r) {
                int bb = m0 + crow0 + r;
                size_t o0 = (size_t)bb * Gg + j0 + lr;
                obase[r] = o0;
                ge0[r] = ge[o0];
                ge1[r] = ge[o0 + 16];
            }
            v4f acc0 = {0.f,0.f,0.f,0.f}, acc1 = {0.f,0.f,0.f,0.f};
            #pragma unroll
            for (int k = 0; k < 32; ++k) {
                v8bf b0 = *reinterpret_cast<const v8bf*>(&wldsT[k][0][l][0]);
                v8bf b1 = *reinterpret_cast<const v8bf*>(&wldsT[k][1][l][0]);
                acc0 = __builtin_amdgcn_mfma_f32_16x16x32_bf16(areg[k], b0, acc0, 0, 0, 0);
                acc1 = __builtin_amdgcn_mfma_f32_16x16x32_bf16(areg[k], b1, acc1, 0, 0, 0);
            }
            #pragma unroll
            for (int r = 0; r < 4; ++r) {
                st_f32_coh(&gates[obase[r]],      acc0[r] + b2f(ge0[r]));
                st_f32_coh(&gates[obase[r] + 16], acc1[r] + b2f(ge1[r]));
            }
        }
        gbar_r7(flags, 2 * t + 1);
        // ---------- Phase S ----------
        {
            bool live = t < dec_b;
            float hn_arr[2];
            const float* g = gates + (size_t)b * Gg;
            // batch the 8 coherent gate loads up-front: one latency exposure
            float gv[8];
            #pragma unroll
            for (int q = 0; q < 2; ++q) {
                int d = tid + q * 256;
                gv[q*4+0] = ld_f32_coh(g + d);
                gv[q*4+1] = ld_f32_coh(g + 512 + d);
                gv[q*4+2] = ld_f32_coh(g + 1024 + d);
                gv[q*4+3] = ld_f32_coh(g + 1536 + d);
            }
            #pragma unroll
            for (int q = 0; q < 2; ++q) {
                int d = tid + q * 256;
                float gi = gv[q*4+0], gf = gv[q*4+1],
                      gg2 = gv[q*4+2], go = gv[q*4+3];
                float c_old = (q == 0) ? cr0 : cr1;
                float si = 1.f / (1.f + expf(-gi));
                float sf = 1.f / (1.f + expf(-gf));
                float so = 1.f / (1.f + expf(-go));
                float cn = sf * c_old + si * tanhf(gg2);
                float hn = so * tanhf(cn);
                hbuf[d] = hn;
                hn_arr[q] = hn;
                Hseq[((size_t)t * Bb + b) * Hh + d] = f2b(hn);
                if (live) {
                    if (q == 0) { cr0 = cn; hr0 = hn; }
                    else        { cr1 = cn; hr1 = hn; }
                }
                xb[Hh + d] = f2b((q == 0) ? hr0 : hr1);
            }
            red1[tid] = hn_arr[0] * swh0 + hn_arr[1] * swh1;
            red2[tid] = hn_arr[0] * wb0 + hn_arr[1] * wb1;
            __syncthreads();
            // RH dot: hbuf once into 8 regs, RH already in registers
            {
                float hv[8];
                #pragma unroll
                for (int j = 0; j < 8; ++j) hv[j] = hbuf[l + j * 64];
                #pragma unroll
                for (int i = 0; i < 9; ++i) {
                    float a = 0.f;
                    #pragma unroll
                    for (int j = 0; j < 8; ++j) a += rhv[i][j] * hv[j];
                    #pragma unroll
                    for (int off = 32; off > 0; off >>= 1) a += __shfl_down(a, off);
                    if (l == 0) rbuf[w + i * 4] = a + rlin[i];
                }
            }
            __syncthreads();
            for (int s = 128; s > 0; s >>= 1) {
                if (tid < s) { red1[tid] += red1[tid + s]; red2[tid] += red2[tid + s]; }
                __syncthreads();
            }
            if (tid < 64) {
                float hs = red1[0] + sumwl;
                float logit = -3.4e38f;
                if (tid < Pp) logit = hs + wrsV + rbuf[tid];
                float mx = logit;
                for (int off = 32; off > 0; off >>= 1) mx = fmaxf(mx, __shfl_down(mx, off));
                mx = __shfl(mx, 0);
                float ex = (tid < Pp) ? expf(logit - mx) : 0.f;
                float sm = ex;
                for (int off = 32; off > 0; off >>= 1) sm += __shfl_down(sm, off);
                sm = __shfl(sm, 0);
                float att = ex / sm;
                float rs = (tid < Pp) ? rbuf[tid] : 0.f;
                for (int off = 32; off > 0; off >>= 1) rs += __shfl_down(rs, off);
                if (tid == 0) rsum[t * Bb + b] = rs + red2[0];
                if (tid < Pp) {
                    attbuf[tid] = att;
                    out_att[((size_t)b * Tm + t) * Pp + tid] = live ? att : 0.f;
                }
            }
            __syncthreads();
            #pragma unroll
            for (int q = 0; q < 2; ++q) {
                int d = tid + q * 256;
                float fbn = 0.f;
                for (int pp = 0; pp < Pp; ++pp)
                    fbn += attbuf[pp] * b2f(plds[pp * Dd + d]);
                if (live) { if (q == 0) fbr0 = fbn; else fbr1 = fbn; }
                xb[d] = f2b((q == 0) ? fbr0 : fbr1);
            }
            __syncthreads();   // xbuf complete -> coherent u32 stores to slot t+1
            {
                unsigned* xg = (unsigned*)(xin2s + (size_t)(t + 1) * (Bb * 1024)
                                                 + (size_t)b * 1024);
                st_u32_coh(xg + tid, xbuf32[tid]);
                st_u32_coh(xg + tid + 256, xbuf32[tid + 256]);
            }
        }
        gbar_r7(flags, 2 * t + 2);
    }
}

// ---------------- fused prep dispatcher (6 independent kernels, bodies unchanged) ----
// blk 0: sort | [1,9): biascat | [9,8009): embcast | [8009,8521): castwc |
// [8521,9161): castwh | [9161,9289): castrh
__global__ __launch_bounds__(256) void k_prep1_r12(
    const int* __restrict__ lengths, int* __restrict__ sort_ind,
    int* __restrict__ dec_i, float* __restrict__ out_dec,
    float* __restrict__ out_sort, int* __restrict__ flags,
    const float* __restrict__ b_ih, const float* __restrict__ b_hh,
    float* __restrict__ bias_cat,
    const float* __restrict__ emb_W, const float* __restrict__ w_W,
    const float* __restrict__ w_b, u16* __restrict__ embp,
    float* __restrict__ w_lin,
    const float* __restrict__ W_ih, const float* __restrict__ W_hh,
    u16* __restrict__ Wc, u16* __restrict__ WihE,
    const float* __restrict__ wh_W, const float* __restrict__ wr_W,
    u16* __restrict__ BtWh, u16* __restrict__ BtWr,
    const float* __restrict__ rh_W, u16* __restrict__ rh_bf)
{
    const int blk = blockIdx.x, tid = threadIdx.x;
    if (blk == 0) {
        __shared__ int len[64];
        if (tid < 64) {
            #pragma unroll
            for (int j = 0; j < 16; ++j) flags[tid * 16 + j] = 0;
            len[tid] = lengths[tid];
        }
        __syncthreads();
        if (tid < 64) {
            int li = len[tid];
            int rank = 0;
            for (int j = 0; j < 64; ++j) {
                int lj = len[j];
                rank += (lj > li) || (lj == li && j < tid);
            }
            sort_ind[rank] = tid;
            dec_i[rank] = li - 1;
            out_sort[rank] = (float)tid;
            out_dec[rank] = (float)(li - 1);
        }
    } else if (blk < 9) {
        int j = (blk - 1) * 256 + tid;
        bias_cat[j] = b_ih[j] + b_hh[j];
    } else if (blk < 8009) {
        int v = (blk - 9) * 4 + (tid >> 6);
        int l = tid & 63;
        float acc = 0.f;
        for (int e = l; e < Ep; e += 64) {
            float x = (e < Ee) ? emb_W[(size_t)v * Ee + e] : 0.f;
            embp[(size_t)v * Ep + e] = f2b(x);
            if (e < Ee) acc += x * w_W[e];
        }
        for (int off = 32; off > 0; off >>= 1) acc += __shfl_down(acc, off);
        if (l == 0) w_lin[v] = acc + w_b[0];
    } else if (blk < 8521) {
        int j = (blk - 8009) * 4 + (tid >> 6);
        int l = tid & 63;
        for (int k = l; k < 1024; k += 64) {
            float v = (k < 512) ? W_ih[(size_t)j * 812 + 300 + k]
                                : W_hh[(size_t)j * 512 + (k - 512)];
            Wc[(size_t)j * 1024 + k] = f2b(v);
        }
        for (int e = l; e < Ep; e += 64) {
            float v = (e < Ee) ? W_ih[(size_t)j * 812 + e] : 0.f;
            WihE[(size_t)j * Ep + e] = f2b(v);
        }
    } else if (blk < 9161) {
        int e = blk - 8521;
        const float* W; u16* O;
        if (e < Ep) { W = wh_W; O = BtWh; }
        else { W = wr_W; O = BtWr; e -= Ep; }
        for (int h = tid; h < Hh; h += 256) {
            float v = (e < Ee) ? W[(size_t)h * Ee + e] : 0.f;
            O[(size_t)e * Hh + h] = f2b(v);
        }
    } else {
        int h = (blk - 9161) * 4 + (tid >> 6);
        int l = tid & 63;
        for (int d = l; d < Dd; d += 64)
            rh_bf[(size_t)h * Dd + d] = f2b(rh_W[(size_t)h * Dd + d]);
    }
}

// ---------------- small kernels ----------------

__global__ void k_gather_r4(const float* __restrict__ h0, const int* __restrict__ captions,
                            const int* __restrict__ sort_ind,
                            float* __restrict__ h_state, float* __restrict__ c_state,
                            float* __restrict__ fb_state, u16* __restrict__ xin2,
                            int* __restrict__ caps_s, float* __restrict__ out_caps)
{
    int b = blockIdx.x, tid = threadIdx.x;
    int src = sort_ind[b];
    for (int d = tid; d < Hh; d += 256) {
        float v = h0[(size_t)src * Hh + d];
        h_state[b * Hh + d] = v;
        c_state[b * Hh + d] = v;
        fb_state[b * Hh + d] = 0.f;
        xin2[(size_t)b * 1024 + d] = 0;
        xin2[(size_t)b * 1024 + Hh + d] = f2b(v);
    }
    if (tid < Tt) {
        int cp = captions[src * Tt + tid];
        caps_s[b * Tt + tid] = cp;
        if (tid >= 1) out_caps[b * Tm + (tid - 1)] = (float)cp;
    }
}

__global__ void k_props_r4(const float* __restrict__ props, const int* __restrict__ sort_ind,
                           const float* __restrict__ wr_b,
                           u16* __restrict__ props_bf, u16* __restrict__ S_bf,
                           float* __restrict__ swrb)
{
    int b = blockIdx.x, tid = threadIdx.x;
    int src = sort_ind[b];
    float s0 = 0.f, s1 = 0.f;
    for (int pp = 0; pp < Pp; ++pp) {
        size_t si = ((size_t)src * Pp + pp) * Dd;
        size_t di = ((size_t)b * Pp + pp) * Dd;
        float v0 = props[si + tid];
        float v1 = props[si + tid + 256];
        props_bf[di + tid] = f2b(v0);
        props_bf[di + tid + 256] = f2b(v1);
        s0 += v0; s1 += v1;
    }
    S_bf[b * Dd + tid] = f2b(s0);
    S_bf[b * Dd + tid + 256] = f2b(s1);
    float part = s0 * wr_b[tid] + s1 * wr_b[tid + 256];
    __shared__ float red[256];
    red[tid] = part;
    __syncthreads();
    for (int s = 128; s > 0; s >>= 1) {
        if (tid < s) red[tid] += red[tid + s];
        __syncthreads();
    }
    if (tid == 0) swrb[b] = red[0];
}

__global__ void k_colsumA_r4(const float* __restrict__ emb_W, float* __restrict__ partial)
{
    int blk = blockIdx.x, e = threadIdx.x; // 320 threads
    float s = 0.f;
    int r0 = blk * 100;
    if (e < Ee)
        for (int r = 0; r < 100; ++r) s += emb_W[(size_t)(r0 + r) * Ee + e];
    partial[blk * Ep + e] = (e < Ee) ? s : 0.f;
}

__global__ void k_colsumB_r4(const float* __restrict__ partial, const float* __restrict__ w_W,
                             const float* __restrict__ w_b,
                             float* __restrict__ colsum, float* __restrict__ sum_wl)
{
    int e = threadIdx.x; // 320 threads
    float s = 0.f;
    for (int b = 0; b < 320; ++b) s += partial[b * Ep + e];
    colsum[e] = s;
    __shared__ float red[512];
    red[e] = (e < Ee) ? s * w_W[e] : 0.f;
    if (e < 192) red[320 + e] = 0.f;
    __syncthreads();
    for (int st = 256; st > 0; st >>= 1) {
        if (e < st) red[e] += red[e + st];
        __syncthreads();
    }
    if (e == 0) sum_wl[0] = red[0] + 32000.f * w_b[0];
}

__global__ void k_sums_r4(const float* __restrict__ colsum,
                          const float* __restrict__ wh_W, const float* __restrict__ wh_b,
                          const float* __restrict__ wr_W, const float* __restrict__ wr_b,
                          float* __restrict__ sum_WH, float* __restrict__ sum_WRp)
{
    int g = blockIdx.x * 64 + threadIdx.x;
    const float* W; const float* bias; float* out; int idx;
    if (g < Hh) { W = wh_W; bias = wh_b; out = sum_WH; idx = g; }
    else { W = wr_W; bias = wr_b; out = sum_WRp; idx = g - Hh; }
    float s = 0.f;
    for (int e = 0; e < Ee; ++e) s += colsum[e] * W[(size_t)idx * Ee + e];
    out[idx] = s + 32000.f * bias[idx];
}

__global__ void k_rlin_r4(const u16* __restrict__ props_bf, const float* __restrict__ r_W,
                          const float* __restrict__ r_b, const float* __restrict__ sum_WRp,
                          float* __restrict__ r_lin, float* __restrict__ wr_sumV)
{
    int b = blockIdx.x;
    int w = threadIdx.x >> 6, l = threadIdx.x & 63;
    for (int pp = w; pp < Pp; pp += 4) {
        const u16* row = props_bf + ((size_t)b * Pp + pp) * Dd;
        float a = 0.f, c = 0.f;
        for (int d = l; d < Dd; d += 64) {
            float x = b2f(row[d]);
            a += x * r_W[d];
            c += x * sum_WRp[d];
        }
        for (int off = 32; off > 0; off >>= 1) {
            a += __shfl_down(a, off);
            c += __shfl_down(c, off);
        }
        if (l == 0) {
            r_lin[b * Pp + pp] = a + r_b[0];
            wr_sumV[b * Pp + pp] = c;
        }
    }
}

__global__ void k_embs_r4(const u16* __restrict__ embp, const int* __restrict__ caps_s,
                          u16* __restrict__ emb_s)
{
    int m = blockIdx.x * 4 + (threadIdx.x >> 6);
    int l = threadIdx.x & 63;
    int t = m >> 6, b = m & 63;
    int cap = caps_s[b * Tt + t];
    cap = cap < 0 ? 0 : (cap > Vv - 1 ? Vv - 1 : cap);
    const u16* src = embp + (size_t)cap * Ep;
    u16* dst = emb_s + (size_t)m * Ep;
    for (int e = l; e < Ep; e += 64) dst[e] = src[e];
}

extern "C" void kernel_launch(void* const* d_in, const int* in_sizes, int n_in,
                              void* d_out, int out_size, void* d_ws, size_t ws_size,
                              hipStream_t stream) {
    float* out = (float*)d_out;   // outputs are FLOAT32 (reference dtype)
    float* out_pred = out;
    float* out_att  = out + (size_t)Bb * Tm * Vv;
    float* out_caps = out_att + (size_t)Bb * Tm * Pp;
    float* out_dec  = out_caps + Bb * Tm;
    float* out_sort = out_dec + Bb;

    // ---- assumption guards (diagnostic sentinels) ----
    if (n_in != 19) {
        k_sentinel_r4<<<32, 256, 0, stream>>>(out_pred, 10240.f);
        return;
    }
    static const int exp_sizes[19] = {
        Bb * Hh, Bb * Pp * Dd, Bb * Tt, Bb, Vv * Ee,
        Gg * (Ee + Dd), Gg * Hh, Gg, Gg,
        Hh * Ee, Hh, Dd * Ee, Dd, Hh * Dd, Hh, Ee, 1, Dd, 1
    };
    for (int i = 0; i < 19; ++i) {
        if (in_sizes[i] != exp_sizes[i]) {
            k_sentinel_r4<<<32, 256, 0, stream>>>(out_pred, 10752.f + 256.f * i);
            return;
        }
    }
    const int exp_out = Bb * Tm * Vv + Bb * Tm * Pp + Bb * Tm + Bb + Bb;
    if (out_size != exp_out) {
        k_sentinel_r4<<<32, 256, 0, stream>>>(out_pred, 11264.f);
        return;
    }

    char* p = (char*)d_ws;
    auto alloc = [&](size_t bytes) -> char* {
        char* r = p;
        p += (bytes + 255) & ~(size_t)255;
        return r;
    };
    int*   i_sort   = (int*)alloc(Bb * 4);
    int*   i_dec    = (int*)alloc(Bb * 4);
    int*   caps_s   = (int*)alloc(Bb * Tt * 4);
    float* h_state  = (float*)alloc(Bb * Hh * 4);
    float* c_state  = (float*)alloc(Bb * Hh * 4);
    float* fb_state = (float*)alloc(Bb * Hh * 4);
    float* swrb     = (float*)alloc(Bb * 4);
    float* gates    = (float*)alloc((size_t)Bb * Gg * 4);
    float* rsum     = (float*)alloc(Tm * Bb * 4);
    float* colsum   = (float*)alloc(Ep * 4);
    float* partialc = (float*)alloc(320 * Ep * 4);
    float* w_lin    = (float*)alloc((size_t)Vv * 4);
    float* sum_WH   = (float*)alloc(Hh * 4);
    float* sum_WRp  = (float*)alloc(Dd * 4);
    float* sum_wl   = (float*)alloc(256);
    float* r_lin    = (float*)alloc(Bb * Pp * 4);
    float* wr_sumV  = (float*)alloc(Bb * Pp * 4);
    float* bias_cat = (float*)alloc(Gg * 4);
    float* RH       = (float*)alloc((size_t)Bb * Pp * Hh * 4);
    int*   flags    = (int*)alloc(Bb * 16 * 4);   // 64 cache lines, one per block
    u16*   gates_e  = (u16*)alloc((size_t)Tm * Bb * Gg * 2);
    u16*   wr_sumP  = (u16*)alloc((size_t)Bb * Vv * 2);
    u16*   embp     = (u16*)alloc((size_t)Vv * Ep * 2);
    u16*   emb_s    = (u16*)alloc((size_t)Tm * Bb * Ep * 2);
    u16*   BtWh     = (u16*)alloc((size_t)Ep * Hh * 2);
    u16*   BtWr     = (u16*)alloc((size_t)Ep * Hh * 2);
    u16*   rh_bf    = (u16*)alloc((size_t)Hh * Dd * 2);
    u16*   WihE     = (u16*)alloc((size_t)Gg * Ep * 2);
    u16*   Wc       = (u16*)alloc((size_t)Gg * 1024 * 2);
    u16*   props_bf = (u16*)alloc((size_t)Bb * Pp * Dd * 2);
    u16*   S_bf     = (u16*)alloc(Bb * Dd * 2);
    u16*   Sw       = (u16*)alloc(Bb * Ep * 2);
    u16*   xin2s    = (u16*)alloc((size_t)(Tm + 1) * Bb * 1024 * 2);  // t-versioned
    u16*   Hseq     = (u16*)alloc((size_t)Tm * Bb * Hh * 2);
    u16*   Hw       = (u16*)alloc((size_t)Tm * Bb * Ep * 2);
    size_t needed = (size_t)(p - (char*)d_ws);
    if (ws_size < needed) {
        k_sentinel_r4<<<32, 256, 0, stream>>>(out_pred, 10496.f);
        return;
    }

    const float* h0      = (const float*)d_in[0];
    const float* props   = (const float*)d_in[1];
    const int*   captions= (const int*)d_in[2];
    const int*   cap_len = (const int*)d_in[3];
    const float* emb_W   = (const float*)d_in[4];
    const float* W_ih    = (const float*)d_in[5];
    const float* W_hh    = (const float*)d_in[6];
    const float* b_ih    = (const float*)d_in[7];
    const float* b_hh    = (const float*)d_in[8];
    const float* wh_W    = (const float*)d_in[9];
    const float* wh_b    = (const float*)d_in[10];
    const float* wr_W    = (const float*)d_in[11];
    const float* wr_b    = (const float*)d_in[12];
    const float* rh_W    = (const float*)d_in[13];
    const float* rh_b    = (const float*)d_in[14];
    const float* w_W     = (const float*)d_in[15];
    const float* w_b     = (const float*)d_in[16];
    const float* r_W     = (const float*)d_in[17];
    const float* r_b     = (const float*)d_in[18];

    // fused prep: sort + biascat + embcast + castwc + castwh + castrh
    k_prep1_r12<<<9289, 256, 0, stream>>>(
        cap_len, i_sort, i_dec, out_dec, out_sort, flags,
        b_ih, b_hh, bias_cat,
        emb_W, w_W, w_b, embp, w_lin,
        W_ih, W_hh, Wc, WihE,
        wh_W, wr_W, BtWh, BtWr,
        rh_W, rh_bf);
    k_colsumA_r4<<<320, 320, 0, stream>>>(emb_W, partialc);
    k_colsumB_r4<<<1, 320, 0, stream>>>(partialc, w_W, w_b, colsum, sum_wl);
    k_sums_r4<<<16, 64, 0, stream>>>(colsum, wh_W, wh_b, wr_W, wr_b, sum_WH, sum_WRp);
    k_gather_r4<<<Bb, 256, 0, stream>>>(h0, captions, i_sort, h_state, c_state,
                                        fb_state, xin2s, caps_s, out_caps);
    k_props_r4<<<Bb, 256, 0, stream>>>(props, i_sort, wr_b, props_bf, S_bf, swrb);
    k_rlin_r4<<<Bb, 256, 0, stream>>>(props_bf, r_W, r_b, sum_WRp, r_lin, wr_sumV);
    k_embs_r4<<<(Tm * Bb) / 4, 256, 0, stream>>>(embp, caps_s, emb_s);

    // gates_e = bf16(emb_s @ WihE^T + (b_ih + b_hh))
    gemm_bt_r4<4><<<dim3(Gg / 64, (Tm * Bb) / 64), 256, 0, stream>>>(
        emb_s, WihE, Ep, Ep, Ep, nullptr, gates_e, Gg,
        bias_cat, nullptr, nullptr, nullptr, nullptr, nullptr);
    // RH = props @ rh_W^T + rh_b
    gemm_bt_r4<0><<<dim3(Hh / 64, (Bb * Pp) / 64), 256, 0, stream>>>(
        props_bf, rh_bf, Dd, Dd, Dd, RH, nullptr, Hh,
        rh_b, nullptr, nullptr, nullptr, nullptr, nullptr);
    // Sw = bf16(S @ wr_W)
    gemm_bt_r4<1><<<dim3(Ep / 64, 1), 256, 0, stream>>>(
        S_bf, BtWr, Dd, Hh, Dd, nullptr, Sw, Ep,
        nullptr, nullptr, nullptr, nullptr, nullptr, nullptr);
    // wr_sumP = bf16(Sw @ embp^T + swrb[b])
    gemm_bt_r4<5><<<dim3(Vv / 64, 1), 256, 0, stream>>>(
        Sw, embp, Ep, Ep, Ep, nullptr, wr_sumP, Vv,
        nullptr, swrb, nullptr, nullptr, nullptr, nullptr);

    // ---- fused 19-step recurrence: one persistent kernel, 64 co-resident blocks ----
    k_loop_r12<<<Bb, 256, 0, stream>>>(Wc, gates_e, gates, sum_WH, sum_wl, wr_sumV,
                                       r_lin, RH, props_bf, i_dec, wh_b,
                                       h_state, c_state, fb_state, xin2s, Hseq,
                                       rsum, out_att, flags);

    // Hw = bf16(Hseq @ wh_W)
    gemm_bt_r4<1><<<dim3(Ep / 64, (Tm * Bb) / 64), 256, 0, stream>>>(
        Hseq, BtWh, Hh, Hh, Hh, nullptr, Hw, Ep,
        nullptr, nullptr, nullptr, nullptr, nullptr, nullptr);
    // predictions (f32, masked, direct to d_out) — LDS-staged 64x256 tile kernel
    k_pred_r10<<<dim3(8 * 304), 256, 0, stream>>>(
        Hw, embp, w_lin, rsum, wr_sumP, i_dec, out_pred);
}